// Round 1
// baseline (564.966 us; speedup 1.0000x reference)
//
#include <hip/hip_runtime.h>
#include <math.h>

// Problem dims (from reference setup_inputs)
#define G_   8
#define T_   4096
#define D_   2048
#define E_   64
#define ROWS (G_*T_)          // 32768
#define BM   64               // rows per block tile
#define BK   32               // K slice per iteration
#define NIT  (D_/BK)          // 64 iterations

__global__ __launch_bounds__(256) void router_kernel(
    const float* __restrict__ tok,   // [ROWS, D]
    const float* __restrict__ noi,   // [ROWS, D]
    const float* __restrict__ wgt,   // [E, D]
    const float* __restrict__ bias,  // [E]
    float* __restrict__ probs,       // [ROWS, E]
    float* __restrict__ masked,      // [ROWS, E]
    float* __restrict__ zloss)       // [1]
{
    __shared__ float xs[BK][BM];     // x tile, transposed [k][m]
    __shared__ float ws[BK][E_];     // weight tile, transposed [k][e]
    __shared__ float abs_row[BM];
    __shared__ float zred[4];

    const int tid  = threadIdx.x;
    const int lrow = tid >> 2;       // 0..63 : row (or expert) this thread loads
    const int lc   = tid & 3;        // 0..3  : float4 column group
    const int ty   = tid >> 4;       // 0..15 : output row group (4 rows)
    const int tx   = tid & 15;       // 0..15 : output col group (4 experts)
    const size_t row0 = (size_t)blockIdx.x * BM;

    const float* tbase = tok + (row0 + (size_t)lrow) * D_ + lc * 4;
    const float* nbase = noi + (row0 + (size_t)lrow) * D_ + lc * 4;
    const float* wbase = wgt + (size_t)lrow * D_ + lc * 4;

    float acc[4][4];
#pragma unroll
    for (int i = 0; i < 4; ++i)
#pragma unroll
        for (int j = 0; j < 4; ++j) acc[i][j] = 0.f;
    float absacc = 0.f;

    // ---- register prefetch of tile 0 ----
    float4 a0 = *(const float4*)(tbase +  0);
    float4 a1 = *(const float4*)(tbase + 16);
    float4 n0 = *(const float4*)(nbase +  0);
    float4 n1 = *(const float4*)(nbase + 16);
    float4 w0 = *(const float4*)(wbase +  0);
    float4 w1 = *(const float4*)(wbase + 16);

    for (int it = 0; it < NIT; ++it) {
        // jitter: x = tok * (0.99 + 0.02*noise)
        float4 x0, x1;
        x0.x = a0.x * (0.99f + 0.02f * n0.x);
        x0.y = a0.y * (0.99f + 0.02f * n0.y);
        x0.z = a0.z * (0.99f + 0.02f * n0.z);
        x0.w = a0.w * (0.99f + 0.02f * n0.w);
        x1.x = a1.x * (0.99f + 0.02f * n1.x);
        x1.y = a1.y * (0.99f + 0.02f * n1.y);
        x1.z = a1.z * (0.99f + 0.02f * n1.z);
        x1.w = a1.w * (0.99f + 0.02f * n1.w);
        absacc += fabsf(x0.x) + fabsf(x0.y) + fabsf(x0.z) + fabsf(x0.w)
                + fabsf(x1.x) + fabsf(x1.y) + fabsf(x1.z) + fabsf(x1.w);

        // store transposed into LDS
        xs[lc*4+0 ][lrow] = x0.x;  xs[lc*4+1 ][lrow] = x0.y;
        xs[lc*4+2 ][lrow] = x0.z;  xs[lc*4+3 ][lrow] = x0.w;
        xs[lc*4+16][lrow] = x1.x;  xs[lc*4+17][lrow] = x1.y;
        xs[lc*4+18][lrow] = x1.z;  xs[lc*4+19][lrow] = x1.w;
        ws[lc*4+0 ][lrow] = w0.x;  ws[lc*4+1 ][lrow] = w0.y;
        ws[lc*4+2 ][lrow] = w0.z;  ws[lc*4+3 ][lrow] = w0.w;
        ws[lc*4+16][lrow] = w1.x;  ws[lc*4+17][lrow] = w1.y;
        ws[lc*4+18][lrow] = w1.z;  ws[lc*4+19][lrow] = w1.w;
        __syncthreads();

        // prefetch next tile (clamped: last iter re-reads current slice, L2-hot)
        {
            int knext = (it + 1 < NIT) ? (it + 1) * BK : it * BK;
            a0 = *(const float4*)(tbase + knext);
            a1 = *(const float4*)(tbase + knext + 16);
            n0 = *(const float4*)(nbase + knext);
            n1 = *(const float4*)(nbase + knext + 16);
            w0 = *(const float4*)(wbase + knext);
            w1 = *(const float4*)(wbase + knext + 16);
        }

        // FMA over the LDS tile
#pragma unroll 8
        for (int k = 0; k < BK; ++k) {
            float4 av = *(const float4*)&xs[k][ty*4];
            float4 bv = *(const float4*)&ws[k][tx*4];
            float aa[4] = {av.x, av.y, av.z, av.w};
            float bb[4] = {bv.x, bv.y, bv.z, bv.w};
#pragma unroll
            for (int i = 0; i < 4; ++i)
#pragma unroll
                for (int j = 0; j < 4; ++j)
                    acc[i][j] = fmaf(aa[i], bb[j], acc[i][j]);
        }
        __syncthreads();
    }

    // ---- per-row |x| sum: reduce the 4 loader threads of each row ----
    absacc += __shfl_xor(absacc, 1);
    absacc += __shfl_xor(absacc, 2);
    if (lc == 0) abs_row[lrow] = absacc;
    __syncthreads();

    // ---- epilogue: softmax, mask, logsumexp, z-loss ----
    float bj[4];
#pragma unroll
    for (int j = 0; j < 4; ++j) bj[j] = bias[tx*4 + j];

    float zpart = 0.f;
#pragma unroll
    for (int i = 0; i < 4; ++i) {
        const size_t gr = row0 + (size_t)(ty*4 + i);
        float l[4];
#pragma unroll
        for (int j = 0; j < 4; ++j) l[j] = acc[i][j] + bj[j];

        // row max across 16 tx-lanes (xor masks 1..8 stay inside the 16-lane group)
        float m = fmaxf(fmaxf(l[0], l[1]), fmaxf(l[2], l[3]));
        m = fmaxf(m, __shfl_xor(m, 1));
        m = fmaxf(m, __shfl_xor(m, 2));
        m = fmaxf(m, __shfl_xor(m, 4));
        m = fmaxf(m, __shfl_xor(m, 8));

        float e[4]; float s = 0.f;
#pragma unroll
        for (int j = 0; j < 4; ++j) { e[j] = expf(l[j] - m); s += e[j]; }
        s += __shfl_xor(s, 1);
        s += __shfl_xor(s, 2);
        s += __shfl_xor(s, 4);
        s += __shfl_xor(s, 8);
        const float rs = 1.f / s;

        float4 pv = { e[0]*rs, e[1]*rs, e[2]*rs, e[3]*rs };
        *(float4*)(probs + gr * E_ + tx*4) = pv;

        const float msk = (abs_row[ty*4 + i] > 0.f) ? 1.f : 0.f;
        float ml[4];
#pragma unroll
        for (int j = 0; j < 4; ++j) ml[j] = l[j] * msk;
        float4 mv = { ml[0], ml[1], ml[2], ml[3] };
        *(float4*)(masked + gr * E_ + tx*4) = mv;

        // logsumexp of masked logits
        float mm = fmaxf(fmaxf(ml[0], ml[1]), fmaxf(ml[2], ml[3]));
        mm = fmaxf(mm, __shfl_xor(mm, 1));
        mm = fmaxf(mm, __shfl_xor(mm, 2));
        mm = fmaxf(mm, __shfl_xor(mm, 4));
        mm = fmaxf(mm, __shfl_xor(mm, 8));
        float ss = 0.f;
#pragma unroll
        for (int j = 0; j < 4; ++j) ss += expf(ml[j] - mm);
        ss += __shfl_xor(ss, 1);
        ss += __shfl_xor(ss, 2);
        ss += __shfl_xor(ss, 4);
        ss += __shfl_xor(ss, 8);
        if (tx == 0) {
            const float lse = mm + logf(ss);
            zpart += lse * lse;
        }
    }

    // block-reduce z partials, one atomic per block
    zpart += __shfl_xor(zpart, 32);
    zpart += __shfl_xor(zpart, 16);
    zpart += __shfl_xor(zpart, 8);
    zpart += __shfl_xor(zpart, 4);
    zpart += __shfl_xor(zpart, 2);
    zpart += __shfl_xor(zpart, 1);
    if ((tid & 63) == 0) zred[tid >> 6] = zpart;
    __syncthreads();
    if (tid == 0) {
        const float z = (zred[0] + zred[1]) + (zred[2] + zred[3]);
        atomicAdd(zloss, z * (1.0f / (float)ROWS));
    }
}

extern "C" void kernel_launch(void* const* d_in, const int* in_sizes, int n_in,
                              void* d_out, int out_size, void* d_ws, size_t ws_size,
                              hipStream_t stream) {
    (void)in_sizes; (void)n_in; (void)ws_size; (void)out_size; (void)d_ws;
    const float* tok  = (const float*)d_in[0];
    const float* noi  = (const float*)d_in[1];
    const float* wgt  = (const float*)d_in[2];
    const float* bias = (const float*)d_in[3];
    // d_in[4] = expert_capacity (unused by the reference outputs)

    float* probs  = (float*)d_out;
    float* masked = probs + (size_t)ROWS * E_;
    float* zloss  = probs + 2 * (size_t)ROWS * E_;

    hipMemsetAsync(zloss, 0, sizeof(float), stream);

    dim3 grid(ROWS / BM);   // 512 blocks
    dim3 block(256);
    router_kernel<<<grid, block, 0, stream>>>(tok, noi, wgt, bias, probs, masked, zloss);
}